// Round 13
// baseline (482.820 us; speedup 1.0000x reference)
//
#include <hip/hip_runtime.h>
#include <hip/hip_bf16.h>

typedef __hip_bfloat16 bf16;
#define DEVI __device__ __forceinline__

// Problem constants
static constexpr int BATCH = 8;
static constexpr int NPT   = 2048;
static constexpr int DMID  = 64;
static constexpr int DEMB  = 256;
static constexpr int NSA   = 4;
static constexpr long STRD = (long)DEMB * NPT;  // 524288
static constexpr long QKS  = (long)NPT * 512;   // per-batch stride of QKt
static constexpr long NN   = (long)NPT * NPT;   // 4194304

typedef __attribute__((ext_vector_type(4))) float f32x4;
typedef __attribute__((ext_vector_type(8))) short bf16x8v;

DEVI f32x4 MFMA16(bf16x8v a, bf16x8v b, f32x4 c) {
  return __builtin_amdgcn_mfma_f32_16x16x32_bf16(a, b, c, 0, 0, 0);
}

DEVI void gload16(const bf16* g, bf16* l) {
  __builtin_amdgcn_global_load_lds(
      (const __attribute__((address_space(1))) void*)g,
      (__attribute__((address_space(3))) void*)l, 16, 0, 0);
}

DEVI float waveReduceSum(float v) {
#pragma unroll
  for (int o = 32; o > 0; o >>= 1) v += __shfl_down(v, o, 64);
  return v;
}
DEVI float blockReduceSum(float v) {
  __shared__ float sm[4];
  int lane = threadIdx.x & 63, wid = threadIdx.x >> 6;
  __syncthreads();
  v = waveReduceSum(v);
  if (lane == 0) sm[wid] = v;
  __syncthreads();
  return sm[0] + sm[1] + sm[2] + sm[3];
}

// ---- fp32 -> bf16 convert ----
__global__ void k_cvt(const float* __restrict__ in, bf16* __restrict__ out, int n) {
  int i = blockIdx.x * 256 + threadIdx.x;
  if (i < n) out[i] = __float2bfloat16(in[i]);
}

// ---- concat-convert Wq,Wk -> WQKb [l][512][256] bf16 ----
__global__ void k_cvtqk(const float* __restrict__ wq, const float* __restrict__ wk,
                        bf16* __restrict__ o) {
  int idx = blockIdx.x * 256 + threadIdx.x;  // NSA*512*256
  int c = idx & 255;
  int r = (idx >> 8) & 511;
  int l = idx >> 17;
  float v = (r < 256) ? wq[((l << 8) + r) * 256 + c] : wk[((l << 8) + (r - 256)) * 256 + c];
  o[idx] = __float2bfloat16(v);
}

// ---- conv1: H1t[b][n][o] = sum_c x[b,n,c]*w1[o,c] + b1[o] ----
__global__ void k_conv1t(const float* __restrict__ x, const float* __restrict__ w1,
                         const float* __restrict__ b1, float* __restrict__ h1t) {
  long idx = (long)blockIdx.x * 256 + threadIdx.x;  // [b*n][o]
  int o = idx & 63;
  long bn = idx >> 6;
  const float* xp = x + bn * 3;
  h1t[idx] = b1[o] + xp[0] * w1[o * 3] + xp[1] * w1[o * 3 + 1] + xp[2] * w1[o * 3 + 2];
}

// ---- BN1 stats on H1t [16384][64] ----
__global__ __launch_bounds__(256) void k_bn1a(const float* __restrict__ h, float* __restrict__ pS,
                                              float* __restrict__ pS2) {
  int c = threadIdx.x & 63, rg = threadIdx.x >> 6;
  long r0 = (long)blockIdx.x * 128 + rg * 32;
  float s = 0.f, s2 = 0.f;
  for (int i = 0; i < 32; ++i) {
    float v = h[(r0 + i) * 64 + c];
    s += v; s2 += v * v;
  }
  __shared__ float smS[256], smS2[256];
  smS[threadIdx.x] = s; smS2[threadIdx.x] = s2;
  __syncthreads();
  if (threadIdx.x < 64) {
    float a = 0.f, b = 0.f;
#pragma unroll
    for (int g = 0; g < 4; ++g) { a += smS[g * 64 + c]; b += smS2[g * 64 + c]; }
    pS[blockIdx.x * 64 + c] = a;
    pS2[blockIdx.x * 64 + c] = b;
  }
}
__global__ void k_bn1b(const float* __restrict__ pS, const float* __restrict__ pS2,
                       const float* __restrict__ g, const float* __restrict__ be,
                       float* __restrict__ sa, float* __restrict__ sb) {
  int c = threadIdx.x;
  if (c >= 64) return;
  float s = 0.f, s2 = 0.f;
  for (int i = 0; i < 128; ++i) { s += pS[i * 64 + c]; s2 += pS2[i * 64 + c]; }
  const float inv = 1.0f / (BATCH * NPT);
  float m = s * inv, var = s2 * inv - m * m;
  float A = rsqrtf(var + 1e-5f) * g[c];
  sa[c] = A; sb[c] = be[c] - m * A;
}
__global__ void k_bn1apply(const float* __restrict__ h, const float* __restrict__ sa,
                           const float* __restrict__ sb, bf16* __restrict__ o) {
  long idx = (long)blockIdx.x * 256 + threadIdx.x;
  int c = idx & 63;
  float v = fmaf(h[idx], sa[c], sb[c]);
  o[idx] = __float2bfloat16(v > 0.f ? v : 0.f);
}

// ---- BN2 stats/apply on H [b][256][2048] fp32 ----
__global__ __launch_bounds__(256) void k_bnstats(const float* __restrict__ h, int Cc,
                                                 const float* __restrict__ g, const float* __restrict__ be,
                                                 float* __restrict__ sa, float* __restrict__ sb) {
  int c = blockIdx.x;
  float s = 0.f, s2 = 0.f;
  for (int b = 0; b < BATCH; ++b) {
    const float* p = h + ((long)(b * Cc + c)) * NPT;
    for (int n = threadIdx.x; n < NPT; n += 256) {
      float v = p[n];
      s += v; s2 += v * v;
    }
  }
  s = blockReduceSum(s);
  s2 = blockReduceSum(s2);
  if (threadIdx.x == 0) {
    const float inv = 1.0f / (BATCH * NPT);
    float m = s * inv, var = s2 * inv - m * m;
    float A = rsqrtf(var + 1e-5f) * g[c];
    sa[c] = A; sb[c] = be[c] - m * A;
  }
}
__global__ void k_bnapply(float* __restrict__ h, const float* __restrict__ sa,
                          const float* __restrict__ sb, int Cc, int total) {
  int i = blockIdx.x * 256 + threadIdx.x;
  if (i >= total) return;
  int c = (i >> 11) & (Cc - 1);
  float v = fmaf(h[i], sa[c], sb[c]);
  h[i] = v > 0.f ? v : 0.f;
}

// ---- tiled transpose+convert: H [b][256][2048] f32 -> Ht [b][2048][256] bf16 ----
__global__ __launch_bounds__(256) void k_tcvt(const float* __restrict__ H, bf16* __restrict__ Ht) {
  __shared__ float t[64][65];
  const float* h = H + (long)blockIdx.z * STRD;
  bf16* o = Ht + (long)blockIdx.z * STRD;
  int n0 = blockIdx.x * 64, c0 = blockIdx.y * 64;
#pragma unroll
  for (int ii = 0; ii < 16; ++ii) {
    int idx = ii * 256 + threadIdx.x;
    int i = idx >> 6, j = idx & 63;
    t[i][j] = h[(long)(c0 + i) * NPT + n0 + j];
  }
  __syncthreads();
#pragma unroll
  for (int ii = 0; ii < 16; ++ii) {
    int idx = ii * 256 + threadIdx.x;
    int i = idx >> 6, j = idx & 63;
    o[(long)(n0 + i) * DEMB + c0 + j] = __float2bfloat16(t[j][i]);
  }
}

// ---- MFMA GEMM, B^T form: C[M][N] = A[M][K] . B[N][K]^T ; 128x128 tile, BK=64 ----
// XOR-swizzled LDS (granule ^= row&7) on both staging-source and read.
// MODE 0: C bf16 = acc + fused column-softmax partials; 1-D grid, z = bid % nz (XCD-pin)
// MODE 1: C bf16 = acc
// MODE 2: C f32 = acc + bias[r]
template <int MODE>
__global__ __launch_bounds__(256) void k_mgemm(
    const bf16* __restrict__ A, long aStr, int ldA,
    const bf16* __restrict__ B, long bStr, int ldB,
    void* __restrict__ Cv, long cStr, int ldC,
    int K,
    const float* __restrict__ bias,
    float* __restrict__ PMo, float* __restrict__ PSo, int nz) {
  __shared__ __align__(16) bf16 sA[128 * 64];
  __shared__ __align__(16) bf16 sB[128 * 64];
  __shared__ float smx[4][64], ssx[4][64];
  int bx, by, bz;
  if constexpr (MODE == 0) {
    bz = blockIdx.x % nz;
    int t = blockIdx.x / nz;
    bx = t & 15;
    by = t >> 4;
  } else {
    bx = blockIdx.x; by = blockIdx.y; bz = blockIdx.z;
  }
  A += aStr * bz;
  B += bStr * bz;
  const int bm = by * 128, bn = bx * 128;
  const int tid = threadIdx.x;
  const int lane = tid & 63, wv = tid >> 6;
  const int wr = (wv >> 1) * 64, wc = (wv & 1) * 64;
  f32x4 acc[4][4] = {};

  for (int k0 = 0; k0 < K; k0 += 64) {
#pragma unroll
    for (int i = 0; i < 4; ++i) {
      int c = i * 256 + tid;
      int row = c >> 3, g = c & 7;
      int gs = (g ^ (row & 7)) * 8;
      gload16(A + (long)(bm + row) * ldA + k0 + gs, sA + c * 8);
      gload16(B + (long)(bn + row) * ldB + k0 + gs, sB + c * 8);
    }
    __syncthreads();
    bf16x8v af[4][2], bfr[4][2];
#pragma unroll
    for (int mi = 0; mi < 4; ++mi)
#pragma unroll
      for (int ks = 0; ks < 2; ++ks) {
        int rA = wr + mi * 16 + (lane & 15);
        int rB = wc + mi * 16 + (lane & 15);
        int g = ks * 4 + (lane >> 4);
        af[mi][ks]  = *(const bf16x8v*)&sA[rA * 64 + ((g ^ (rA & 7)) * 8)];
        bfr[mi][ks] = *(const bf16x8v*)&sB[rB * 64 + ((g ^ (rB & 7)) * 8)];
      }
#pragma unroll
    for (int ks = 0; ks < 2; ++ks)
#pragma unroll
      for (int mi = 0; mi < 4; ++mi)
#pragma unroll
        for (int ni = 0; ni < 4; ++ni)
          acc[mi][ni] = MFMA16(af[mi][ks], bfr[ni][ks], acc[mi][ni]);
    __syncthreads();
  }

  const int rb = (lane >> 4) * 4, cb = lane & 15;
  if constexpr (MODE == 0 || MODE == 1) {
    bf16* C = (bf16*)Cv + cStr * bz;
#pragma unroll
    for (int mi = 0; mi < 4; ++mi)
#pragma unroll
      for (int ni = 0; ni < 4; ++ni) {
        int r0 = bm + wr + mi * 16 + rb, c0 = bn + wc + ni * 16 + cb;
#pragma unroll
        for (int k = 0; k < 4; ++k)
          C[(long)(r0 + k) * ldC + c0] = __float2bfloat16(acc[mi][ni][k]);
      }
  } else {
    float* C = (float*)Cv + cStr * bz;
#pragma unroll
    for (int mi = 0; mi < 4; ++mi)
#pragma unroll
      for (int ni = 0; ni < 4; ++ni) {
        int r0 = bm + wr + mi * 16 + rb, c0 = bn + wc + ni * 16 + cb;
#pragma unroll
        for (int k = 0; k < 4; ++k) {
          int r = r0 + k;
          C[(long)r * ldC + c0] = acc[mi][ni][k] + bias[r];
        }
      }
  }

  if constexpr (MODE == 0) {
    // per-column (over this block's 128 rows) online-softmax partials (exact fp32)
    float cm[4], cs[4];
#pragma unroll
    for (int ni = 0; ni < 4; ++ni) {
      float m = -3.0e38f;
#pragma unroll
      for (int mi = 0; mi < 4; ++mi)
#pragma unroll
        for (int k = 0; k < 4; ++k) m = fmaxf(m, acc[mi][ni][k]);
      float s = 0.f;
#pragma unroll
      for (int mi = 0; mi < 4; ++mi)
#pragma unroll
        for (int k = 0; k < 4; ++k) s += __expf(acc[mi][ni][k] - m);
#pragma unroll
      for (int off = 16; off <= 32; off <<= 1) {
        float mo = __shfl_xor(m, off, 64);
        float so = __shfl_xor(s, off, 64);
        float M = fmaxf(m, mo);
        s = s * __expf(m - M) + so * __expf(mo - M);
        m = M;
      }
      cm[ni] = m; cs[ni] = s;
    }
    __syncthreads();  // LDS reads of K-loop complete; reuse smx/ssx safely
    if (lane < 16) {
#pragma unroll
      for (int ni = 0; ni < 4; ++ni) {
        smx[wv][ni * 16 + lane] = cm[ni];
        ssx[wv][ni * 16 + lane] = cs[ni];
      }
    }
    __syncthreads();
    if (tid < 128) {
      int half = tid >> 6, c64 = tid & 63;
      float m1 = smx[half][c64], s1 = ssx[half][c64];
      float m2 = smx[half + 2][c64], s2 = ssx[half + 2][c64];
      float M = fmaxf(m1, m2);
      float S = s1 * __expf(m1 - M) + s2 * __expf(m2 - M);
      long o = ((long)bz * 16 + by) * NPT + bn + half * 64 + c64;
      PMo[o] = M;
      PSo[o] = S;
    }
  }
}

// ---- combine 16 partials per column -> CM, CSi ----
__global__ void k_cms_fin(const float* __restrict__ PM, const float* __restrict__ PS,
                          float* __restrict__ CM, float* __restrict__ CSi) {
  long idx = (long)blockIdx.x * 256 + threadIdx.x;  // [G*NPT]
  long z = idx >> 11;
  int n = idx & (NPT - 1);
  const float* pm = PM + z * 16 * NPT + n;
  const float* ps = PS + z * 16 * NPT + n;
  float m = -3.0e38f;
#pragma unroll
  for (int y = 0; y < 16; ++y) m = fmaxf(m, pm[(long)y * NPT]);
  float s = 0.f;
#pragma unroll
  for (int y = 0; y < 16; ++y) s += ps[(long)y * NPT] * __expf(pm[(long)y * NPT] - m);
  CM[idx] = m;
  CSi[idx] = 1.0f / s;
}

// ---- fused normalize + rowsum + V.P GEMM ----
// F bf16; tile 256e x 64m; 512 threads = 8 waves (4e x 2m); grid 32*nz,
// z = bid % nz pins each batch's V to one XCD's L2.
// V triple-buffered, staged TWO steps ahead; per-step sync is
// counted s_waitcnt vmcnt(4) + lgkmcnt(0) + s_barrier (T3/T4): V staging
// stays in flight across barriers, only the 2-steps-ago staging must land.
// Per step issues exactly 5 vmem ops (1 F-load + 4 gload_lds), so
// outstanding<=4  =>  the staging issued 2 steps ago has retired.
__global__ __launch_bounds__(512) void k_vp(const bf16* __restrict__ F,
                                            const float* __restrict__ CM,
                                            const float* __restrict__ CSi,
                                            const bf16* __restrict__ V,
                                            float* __restrict__ H, int nz) {
  __shared__ __align__(16) bf16 sA[3][256 * 64];  // V tiles (triple-buffered)
  __shared__ __align__(16) bf16 sB[2][64 * 64];   // PT tiles (double-buffered)
  __shared__ float rsLds[64][8];
  __shared__ float Sv[64];
  __shared__ float smCM[NPT], smCS[NPT];
  const int z = blockIdx.x % nz;
  const int m0 = (blockIdx.x / nz) * 64;
  const int tid = threadIdx.x;
  const int lane = tid & 63, wv = tid >> 6;
  const int we = wv & 3;   // e-quarter 0..3 (64 rows)
  const int wm = wv >> 2;  // m-half 0..1 (32 cols)
  const int fr = tid >> 3; // F row 0..63
  const int fq = tid & 7;  // F col chunk 0..7
  const bf16* Vz = V + (long)z * STRD;
  const bf16* Frp = F + (long)z * NN + (long)(m0 + fr) * NPT + fq * 8;
  f32x4 acc[4][2] = {};
  float rs = 0.f;
  bf16x8v fvA, fvB;

  // one-time: stage CM/CSi for this batch into LDS (16 KB)
  {
    const float* cmz = CM + (long)z * NPT;
    const float* csz = CSi + (long)z * NPT;
#pragma unroll
    for (int i = 0; i < 4; ++i) {
      int idx = i * 512 + tid;
      smCM[idx] = cmz[idx];
      smCS[idx] = csz[idx];
    }
  }

#define LOADF(FREG, N0) FREG = *(const bf16x8v*)(Frp + ((N0) & 2047));

  // EXPW: exp of register F chunk (scales from LDS) -> sB[buf]; accumulate rs
#define EXPW(BUF, FREG, N0)                                                    \
  {                                                                            \
    float mv[8], cv[8];                                                        \
    *(float4*)&mv[0] = *(const float4*)&smCM[(N0) + fq * 8];                   \
    *(float4*)&mv[4] = *(const float4*)&smCM[(N0) + fq * 8 + 4];               \
    *(float4*)&cv[0] = *(const float4*)&smCS[(N0) + fq * 8];                   \
    *(float4*)&cv[4] = *(const float4*)&smCS[(N0) + fq * 8 + 4];               \
    bf16 tb[8];                                                                \
    _Pragma("unroll") for (int i = 0; i < 8; ++i) {                            \
      float fvi = __uint_as_float((unsigned)(unsigned short)FREG[i] << 16);    \
      float pv = __expf(fvi - mv[i]) * cv[i];                                  \
      rs += pv;                                                                \
      tb[i] = __float2bfloat16(pv);                                            \
    }                                                                          \
    *(bf16x8v*)&sB[BUF][fr * 64 + ((fq ^ (fr & 7)) * 8)] = *(bf16x8v*)tb;      \
  }

  // STAGEV: issue 4 global_load_lds of V column-chunk into sA[buf] (512 thr)
#define STAGEV(BUF, N0)                                                        \
  _Pragma("unroll") for (int i = 0; i < 4; ++i) {                              \
    int c = i * 512 + tid;                                                     \
    int row = c >> 3, g = c & 7;                                               \
    gload16(Vz + (long)row * NPT + ((N0) & 2047) + ((g ^ (row & 7)) * 8),      \
            &sA[BUF][c * 8]);                                                  \
  }

  // counted-vmcnt step sync: only the 2-steps-ago V staging must have landed.
#define WAITBAR                                                                \
  asm volatile("s_waitcnt vmcnt(4) lgkmcnt(0)" ::: "memory");                  \
  __builtin_amdgcn_s_barrier();                                                \
  __builtin_amdgcn_sched_barrier(0);

  // MFMA on current buffers
#define MFMA_STEP(CA, PB)                                                      \
  {                                                                            \
    bf16x8v bfr[2][2];                                                         \
    _Pragma("unroll") for (int ni = 0; ni < 2; ++ni)                           \
      _Pragma("unroll") for (int ks = 0; ks < 2; ++ks) {                       \
        int rB = wm * 32 + ni * 16 + (lane & 15);                              \
        int g = ks * 4 + (lane >> 4);                                          \
        bfr[ni][ks] = *(const bf16x8v*)&sB[PB][rB * 64 + ((g ^ (rB & 7)) * 8)]; \
      }                                                                        \
    _Pragma("unroll") for (int mi = 0; mi < 4; ++mi)                           \
      _Pragma("unroll") for (int ks = 0; ks < 2; ++ks) {                       \
        int rA = we * 64 + mi * 16 + (lane & 15);                              \
        int g = ks * 4 + (lane >> 4);                                          \
        bf16x8v af = *(const bf16x8v*)&sA[CA][rA * 64 + ((g ^ (rA & 7)) * 8)]; \
        _Pragma("unroll") for (int ni = 0; ni < 2; ++ni)                       \
          acc[mi][ni] = MFMA16(af, bfr[ni][ks], acc[mi][ni]);                  \
      }                                                                        \
  }

  // prologue: V(0)->sA[0], V(1)->sA[1]; F(0),F(1) in regs; PT(0)->sB[0]
  LOADF(fvA, 0)
  LOADF(fvB, 64)
  STAGEV(0, 0)
  STAGEV(1, 64)
  __syncthreads();  // scales + V(0),V(1) + F regs all landed
  EXPW(0, fvA, 0)
  __syncthreads();  // PT(0) visible to all waves

  int c0 = 0;
  for (int it = 0; it < 16; ++it) {
    int c1 = c0 + 1; if (c1 == 3) c1 = 0;
    int c2 = c1 + 1; if (c2 == 3) c2 = 0;
    const int sn0 = 2 * it, nn0 = sn0 * 64;
    // even step sn0: read sA[c0], sB[0]; stage V(sn0+2)->sA[c2]; PT(sn0+1)->sB[1]
    LOADF(fvA, nn0 + 128)
    STAGEV(c2, nn0 + 128)
    EXPW(1, fvB, nn0 + 64)
    MFMA_STEP(c0, 0)
    WAITBAR
    // odd step sn0+1: read sA[c1], sB[1]; stage V(sn0+3)->sA[c0]; PT(sn0+2)->sB[0]
    LOADF(fvB, nn0 + 192)
    STAGEV(c0, nn0 + 192)
    if (sn0 + 2 < 32) EXPW(0, fvA, nn0 + 128)
    MFMA_STEP(c1, 1)
    WAITBAR
    c0 = c2;
  }
#undef MFMA_STEP
#undef WAITBAR
#undef STAGEV
#undef EXPW
#undef LOADF

  rsLds[fr][fq] = rs;
  __syncthreads();
  if (tid < 64) {
    float R = 0.f;
#pragma unroll
    for (int q = 0; q < 8; ++q) R += rsLds[tid][q];
    Sv[tid] = 1.0f / (1e-9f + R);
  }
  __syncthreads();

  float* Hz = H + (long)z * STRD;
  const int rb = (lane >> 4) * 4, cb = lane & 15;
#pragma unroll
  for (int mi = 0; mi < 4; ++mi) {
    int e0 = we * 64 + mi * 16 + rb;
#pragma unroll
    for (int ni = 0; ni < 2; ++ni) {
      int c = wm * 32 + ni * 16 + cb;
      float scl = Sv[c];
#pragma unroll
      for (int k = 0; k < 4; ++k)
        Hz[(long)(e0 + k) * NPT + m0 + c] += acc[mi][ni][k] * scl;
    }
  }
}

// ---- pooled[b,n] = mean over e of H[b,e,n] ----
__global__ void k_pool(const float* __restrict__ H, float* __restrict__ pooled) {
  int i = blockIdx.x * 256 + threadIdx.x;
  if (i >= BATCH * NPT) return;
  int b = i >> 11, n = i & (NPT - 1);
  const float* p = H + (long)b * STRD + n;
  float s = 0.f;
  for (int e = 0; e < DEMB; ++e) s += p[(long)e * NPT];
  pooled[i] = s * (1.0f / DEMB);
}

// ---- fc1: one block per output row j; w row read ONCE, all 8 batches ----
__global__ __launch_bounds__(256) void k_fc1(const float* __restrict__ pooled,
                                             const float* __restrict__ w, const float* __restrict__ bias,
                                             float* __restrict__ f) {
  int j = blockIdx.x;
  const float* wr = w + (long)j * NPT;
  int n0 = threadIdx.x * 8;
  float wl[8];
  *(float4*)&wl[0] = *(const float4*)(wr + n0);
  *(float4*)&wl[4] = *(const float4*)(wr + n0 + 4);
  float part[8];
#pragma unroll
  for (int b = 0; b < 8; ++b) {
    const float* pp = pooled + (long)b * NPT + n0;
    float4 p0 = *(const float4*)pp, p1 = *(const float4*)(pp + 4);
    part[b] = wl[0] * p0.x + wl[1] * p0.y + wl[2] * p0.z + wl[3] * p0.w +
              wl[4] * p1.x + wl[5] * p1.y + wl[6] * p1.z + wl[7] * p1.w;
  }
#pragma unroll
  for (int b = 0; b < 8; ++b) {
    float s = blockReduceSum(part[b]);
    if (threadIdx.x == 0) {
      s += bias[j];
      f[(long)b * NPT + j] = s > 0.f ? s : 0.f;
    }
  }
}

// ---- fc2 ----
__global__ __launch_bounds__(256) void k_fc2(const float* __restrict__ f,
                                             const float* __restrict__ w, const float* __restrict__ bias,
                                             float* __restrict__ out) {
  int b = blockIdx.x;
  float s = 0.f;
  for (int j = threadIdx.x; j < NPT; j += 256) s += f[(long)b * NPT + j] * w[j];
  s = blockReduceSum(s);
  if (threadIdx.x == 0) out[b] = s + bias[0];
}

extern "C" void kernel_launch(void* const* d_in, const int* in_sizes, int n_in,
                              void* d_out, int out_size, void* d_ws, size_t ws_size,
                              hipStream_t stream) {
  const float* X    = (const float*)d_in[0];
  const float* W1   = (const float*)d_in[1];
  const float* B1   = (const float*)d_in[2];
  const float* G1   = (const float*)d_in[3];
  const float* BE1  = (const float*)d_in[4];
  const float* W2   = (const float*)d_in[5];
  const float* B2   = (const float*)d_in[6];
  const float* G2   = (const float*)d_in[7];
  const float* BE2  = (const float*)d_in[8];
  const float* WQ   = (const float*)d_in[9];
  const float* WK   = (const float*)d_in[10];
  const float* WV   = (const float*)d_in[11];
  const float* FC1W = (const float*)d_in[12];
  const float* FC1B = (const float*)d_in[13];
  const float* FC2W = (const float*)d_in[14];
  const float* FC2B = (const float*)d_in[15];
  float* OUT = (float*)d_out;

  // ---- workspace carve-out ----
  char* p = (char*)d_ws;
  auto alloc = [&](size_t bytes) -> char* {
    char* r = p;
    p += (bytes + 255) & ~(size_t)255;
    return r;
  };
  float* H1t  = (float*)alloc((size_t)BATCH * NPT * DMID * 4);
  bf16*  H1tb = (bf16*)alloc((size_t)BATCH * NPT * DMID * 2);
  float* H    = (float*)alloc((size_t)BATCH * STRD * 4);
  bf16*  Ht   = (bf16*)alloc((size_t)BATCH * STRD * 2);
  bf16*  QKt  = (bf16*)alloc((size_t)BATCH * QKS * 2);   // [b][n][512] = Q(0..255) | K(256..511)
  bf16*  Vb   = (bf16*)alloc((size_t)BATCH * STRD * 2);
  bf16*  W2b  = (bf16*)alloc((size_t)DEMB * DMID * 2);
  bf16*  WQKb = (bf16*)alloc((size_t)NSA * 512 * DEMB * 2);
  bf16*  WVb  = (bf16*)alloc((size_t)NSA * DEMB * DEMB * 2);
  float* pS   = (float*)alloc(128 * 64 * 4);
  float* pS2  = (float*)alloc(128 * 64 * 4);
  float* sa1  = (float*)alloc(64 * 4);
  float* sb1  = (float*)alloc(64 * 4);
  float* sa2  = (float*)alloc(256 * 4);
  float* sb2  = (float*)alloc(256 * 4);
  float* CM   = (float*)alloc((size_t)BATCH * NPT * 4);
  float* CSi  = (float*)alloc((size_t)BATCH * NPT * 4);
  float* PM   = (float*)alloc((size_t)BATCH * 16 * NPT * 4);
  float* PSm  = (float*)alloc((size_t)BATCH * 16 * NPT * 4);
  float* POOL = (float*)alloc((size_t)BATCH * NPT * 4);
  float* FH   = (float*)alloc((size_t)BATCH * NPT * 4);
  size_t used = (size_t)(p - (char*)d_ws);
  const size_t per_g = (size_t)NN * 2;  // F bf16 (8MB per batch)
  int G = 8;
  while (G > 1 && used + (size_t)G * per_g + 1024 > ws_size) G >>= 1;
  bf16* F = (bf16*)alloc((size_t)G * NN * 2);

  // ---- weight converts ----
  k_cvt<<<(DEMB * DMID + 255) / 256, 256, 0, stream>>>(W2, W2b, DEMB * DMID);
  int nqk = NSA * 512 * DEMB;
  k_cvtqk<<<nqk / 256, 256, 0, stream>>>(WQ, WK, WQKb);
  int nw = NSA * DEMB * DEMB;
  k_cvt<<<(nw + 255) / 256, 256, 0, stream>>>(WV, WVb, nw);

  // ---- conv1 + BN1 + ReLU (-> H1tb bf16 [b][n][64]) ----
  long szh1 = (long)BATCH * NPT * DMID;
  k_conv1t<<<(int)(szh1 / 256), 256, 0, stream>>>(X, W1, B1, H1t);
  k_bn1a<<<128, 256, 0, stream>>>(H1t, pS, pS2);
  k_bn1b<<<1, 64, 0, stream>>>(pS, pS2, G1, BE1, sa1, sb1);
  k_bn1apply<<<(int)(szh1 / 256), 256, 0, stream>>>(H1t, sa1, sb1, H1tb);

  // ---- conv2 (MFMA) + BN2 + ReLU -> H fp32 [b][256][2048] ----
  k_mgemm<2><<<dim3(16, 2, 8), 256, 0, stream>>>(W2b, 0, DMID, H1tb, (long)NPT * DMID, DMID,
                                                 H, STRD, NPT, DMID, B2, nullptr, nullptr, 0);
  k_bnstats<<<DEMB, 256, 0, stream>>>(H, DEMB, G2, BE2, sa2, sb2);
  k_bnapply<<<(int)(BATCH * STRD / 256), 256, 0, stream>>>(H, sa2, sb2, DEMB, (int)(BATCH * STRD));

  // ---- SA layers ----
  for (int l = 0; l < NSA; ++l) {
    k_tcvt<<<dim3(32, 4, 8), 256, 0, stream>>>(H, Ht);
    // QKt[n][0..511] = Ht . [Wq;Wk]^T  : A=Ht (M=2048), B=WQK (N=512)
    k_mgemm<1><<<dim3(4, 16, 8), 256, 0, stream>>>(Ht, STRD, DEMB, WQKb + (long)l * 512 * DEMB, 0, DEMB,
                                                   QKt, QKS, 512, DEMB, nullptr, nullptr, nullptr, 0);
    // V[e][n] : A=Wv (M=256), B=Ht (N=2048)
    k_mgemm<1><<<dim3(16, 2, 8), 256, 0, stream>>>(WVb + (long)l * DEMB * DEMB, 0, DEMB, Ht, STRD, DEMB,
                                                   Vb, STRD, NPT, DEMB, nullptr, nullptr, nullptr, 0);
    for (int b0 = 0; b0 < BATCH; b0 += G) {
      // F[m][n] = sum_a Kt[m][a] Qt[n][a] (= E^T), bf16 + fused exact column stats
      // 1-D grid, z = bid % G pins each batch's QKt panels to one XCD's L2
      k_mgemm<0><<<dim3(256 * G), 256, 0, stream>>>(QKt + 256 + b0 * QKS, QKS, 512,
                                                    QKt + b0 * QKS, QKS, 512,
                                                    F, NN, NPT, DEMB, nullptr, PM, PSm, G);
      k_cms_fin<<<G * NPT / 256, 256, 0, stream>>>(PM, PSm, CM, CSi);
      // H[e][m] += S[m] * sum_n V[e][n] PT[m][n]  (PT from bf16 F on the fly)
      k_vp<<<dim3(32 * G), 512, 0, stream>>>(F, CM, CSi, Vb + b0 * STRD, H + b0 * STRD, G);
    }
  }

  // ---- head ----
  k_pool<<<(BATCH * NPT) / 256, 256, 0, stream>>>(H, POOL);
  k_fc1<<<NPT, 256, 0, stream>>>(POOL, FC1W, FC1B, FH);
  k_fc2<<<BATCH, 256, 0, stream>>>(FH, FC2W, FC2B, OUT);
}

// Round 14
// 461.705 us; speedup vs baseline: 1.0457x; 1.0457x over previous
//
#include <hip/hip_runtime.h>
#include <hip/hip_bf16.h>

typedef __hip_bfloat16 bf16;
#define DEVI __device__ __forceinline__

// Problem constants
static constexpr int BATCH = 8;
static constexpr int NPT   = 2048;
static constexpr int DMID  = 64;
static constexpr int DEMB  = 256;
static constexpr int NSA   = 4;
static constexpr long STRD = (long)DEMB * NPT;  // 524288
static constexpr long QKS  = (long)NPT * 512;   // per-batch stride of QKt
static constexpr long NN   = (long)NPT * NPT;   // 4194304

typedef __attribute__((ext_vector_type(4))) float f32x4;
typedef __attribute__((ext_vector_type(8))) short bf16x8v;

DEVI f32x4 MFMA16(bf16x8v a, bf16x8v b, f32x4 c) {
  return __builtin_amdgcn_mfma_f32_16x16x32_bf16(a, b, c, 0, 0, 0);
}

DEVI void gload16(const bf16* g, bf16* l) {
  __builtin_amdgcn_global_load_lds(
      (const __attribute__((address_space(1))) void*)g,
      (__attribute__((address_space(3))) void*)l, 16, 0, 0);
}

DEVI float waveReduceSum(float v) {
#pragma unroll
  for (int o = 32; o > 0; o >>= 1) v += __shfl_down(v, o, 64);
  return v;
}
DEVI float blockReduceSum(float v) {
  __shared__ float sm[4];
  int lane = threadIdx.x & 63, wid = threadIdx.x >> 6;
  __syncthreads();
  v = waveReduceSum(v);
  if (lane == 0) sm[wid] = v;
  __syncthreads();
  return sm[0] + sm[1] + sm[2] + sm[3];
}

// ---- fp32 -> bf16 convert ----
__global__ void k_cvt(const float* __restrict__ in, bf16* __restrict__ out, int n) {
  int i = blockIdx.x * 256 + threadIdx.x;
  if (i < n) out[i] = __float2bfloat16(in[i]);
}

// ---- concat-convert Wq,Wk -> WQKb [l][512][256] bf16 ----
__global__ void k_cvtqk(const float* __restrict__ wq, const float* __restrict__ wk,
                        bf16* __restrict__ o) {
  int idx = blockIdx.x * 256 + threadIdx.x;  // NSA*512*256
  int c = idx & 255;
  int r = (idx >> 8) & 511;
  int l = idx >> 17;
  float v = (r < 256) ? wq[((l << 8) + r) * 256 + c] : wk[((l << 8) + (r - 256)) * 256 + c];
  o[idx] = __float2bfloat16(v);
}

// ---- conv1: H1t[b][n][o] = sum_c x[b,n,c]*w1[o,c] + b1[o] ----
__global__ void k_conv1t(const float* __restrict__ x, const float* __restrict__ w1,
                         const float* __restrict__ b1, float* __restrict__ h1t) {
  long idx = (long)blockIdx.x * 256 + threadIdx.x;  // [b*n][o]
  int o = idx & 63;
  long bn = idx >> 6;
  const float* xp = x + bn * 3;
  h1t[idx] = b1[o] + xp[0] * w1[o * 3] + xp[1] * w1[o * 3 + 1] + xp[2] * w1[o * 3 + 2];
}

// ---- BN1 stats on H1t [16384][64] ----
__global__ __launch_bounds__(256) void k_bn1a(const float* __restrict__ h, float* __restrict__ pS,
                                              float* __restrict__ pS2) {
  int c = threadIdx.x & 63, rg = threadIdx.x >> 6;
  long r0 = (long)blockIdx.x * 128 + rg * 32;
  float s = 0.f, s2 = 0.f;
  for (int i = 0; i < 32; ++i) {
    float v = h[(r0 + i) * 64 + c];
    s += v; s2 += v * v;
  }
  __shared__ float smS[256], smS2[256];
  smS[threadIdx.x] = s; smS2[threadIdx.x] = s2;
  __syncthreads();
  if (threadIdx.x < 64) {
    float a = 0.f, b = 0.f;
#pragma unroll
    for (int g = 0; g < 4; ++g) { a += smS[g * 64 + c]; b += smS2[g * 64 + c]; }
    pS[blockIdx.x * 64 + c] = a;
    pS2[blockIdx.x * 64 + c] = b;
  }
}
__global__ void k_bn1b(const float* __restrict__ pS, const float* __restrict__ pS2,
                       const float* __restrict__ g, const float* __restrict__ be,
                       float* __restrict__ sa, float* __restrict__ sb) {
  int c = threadIdx.x;
  if (c >= 64) return;
  float s = 0.f, s2 = 0.f;
  for (int i = 0; i < 128; ++i) { s += pS[i * 64 + c]; s2 += pS2[i * 64 + c]; }
  const float inv = 1.0f / (BATCH * NPT);
  float m = s * inv, var = s2 * inv - m * m;
  float A = rsqrtf(var + 1e-5f) * g[c];
  sa[c] = A; sb[c] = be[c] - m * A;
}
__global__ void k_bn1apply(const float* __restrict__ h, const float* __restrict__ sa,
                           const float* __restrict__ sb, bf16* __restrict__ o) {
  long idx = (long)blockIdx.x * 256 + threadIdx.x;
  int c = idx & 63;
  float v = fmaf(h[idx], sa[c], sb[c]);
  o[idx] = __float2bfloat16(v > 0.f ? v : 0.f);
}

// ---- BN2 stats/apply on H [b][256][2048] fp32 ----
__global__ __launch_bounds__(256) void k_bnstats(const float* __restrict__ h, int Cc,
                                                 const float* __restrict__ g, const float* __restrict__ be,
                                                 float* __restrict__ sa, float* __restrict__ sb) {
  int c = blockIdx.x;
  float s = 0.f, s2 = 0.f;
  for (int b = 0; b < BATCH; ++b) {
    const float* p = h + ((long)(b * Cc + c)) * NPT;
    for (int n = threadIdx.x; n < NPT; n += 256) {
      float v = p[n];
      s += v; s2 += v * v;
    }
  }
  s = blockReduceSum(s);
  s2 = blockReduceSum(s2);
  if (threadIdx.x == 0) {
    const float inv = 1.0f / (BATCH * NPT);
    float m = s * inv, var = s2 * inv - m * m;
    float A = rsqrtf(var + 1e-5f) * g[c];
    sa[c] = A; sb[c] = be[c] - m * A;
  }
}
__global__ void k_bnapply(float* __restrict__ h, const float* __restrict__ sa,
                          const float* __restrict__ sb, int Cc, int total) {
  int i = blockIdx.x * 256 + threadIdx.x;
  if (i >= total) return;
  int c = (i >> 11) & (Cc - 1);
  float v = fmaf(h[i], sa[c], sb[c]);
  h[i] = v > 0.f ? v : 0.f;
}

// ---- tiled transpose+convert: H [b][256][2048] f32 -> Ht [b][2048][256] bf16 ----
__global__ __launch_bounds__(256) void k_tcvt(const float* __restrict__ H, bf16* __restrict__ Ht) {
  __shared__ float t[64][65];
  const float* h = H + (long)blockIdx.z * STRD;
  bf16* o = Ht + (long)blockIdx.z * STRD;
  int n0 = blockIdx.x * 64, c0 = blockIdx.y * 64;
#pragma unroll
  for (int ii = 0; ii < 16; ++ii) {
    int idx = ii * 256 + threadIdx.x;
    int i = idx >> 6, j = idx & 63;
    t[i][j] = h[(long)(c0 + i) * NPT + n0 + j];
  }
  __syncthreads();
#pragma unroll
  for (int ii = 0; ii < 16; ++ii) {
    int idx = ii * 256 + threadIdx.x;
    int i = idx >> 6, j = idx & 63;
    o[(long)(n0 + i) * DEMB + c0 + j] = __float2bfloat16(t[j][i]);
  }
}

// ---- MFMA GEMM, B^T form: C[M][N] = A[M][K] . B[N][K]^T ; 128x128 tile, BK=64 ----
// XOR-swizzled LDS (granule ^= row&7) on both staging-source and read.
// MODE 0: C bf16 = acc + fused column-softmax partials; 1-D grid, z = bid % nz (XCD-pin)
// MODE 1: C bf16 = acc
// MODE 2: C f32 = acc + bias[r]
template <int MODE>
__global__ __launch_bounds__(256) void k_mgemm(
    const bf16* __restrict__ A, long aStr, int ldA,
    const bf16* __restrict__ B, long bStr, int ldB,
    void* __restrict__ Cv, long cStr, int ldC,
    int K,
    const float* __restrict__ bias,
    float* __restrict__ PMo, float* __restrict__ PSo, int nz) {
  __shared__ __align__(16) bf16 sA[128 * 64];
  __shared__ __align__(16) bf16 sB[128 * 64];
  __shared__ float smx[4][64], ssx[4][64];
  int bx, by, bz;
  if constexpr (MODE == 0) {
    bz = blockIdx.x % nz;
    int t = blockIdx.x / nz;
    bx = t & 15;
    by = t >> 4;
  } else {
    bx = blockIdx.x; by = blockIdx.y; bz = blockIdx.z;
  }
  A += aStr * bz;
  B += bStr * bz;
  const int bm = by * 128, bn = bx * 128;
  const int tid = threadIdx.x;
  const int lane = tid & 63, wv = tid >> 6;
  const int wr = (wv >> 1) * 64, wc = (wv & 1) * 64;
  f32x4 acc[4][4] = {};

  for (int k0 = 0; k0 < K; k0 += 64) {
#pragma unroll
    for (int i = 0; i < 4; ++i) {
      int c = i * 256 + tid;
      int row = c >> 3, g = c & 7;
      int gs = (g ^ (row & 7)) * 8;
      gload16(A + (long)(bm + row) * ldA + k0 + gs, sA + c * 8);
      gload16(B + (long)(bn + row) * ldB + k0 + gs, sB + c * 8);
    }
    __syncthreads();
    bf16x8v af[4][2], bfr[4][2];
#pragma unroll
    for (int mi = 0; mi < 4; ++mi)
#pragma unroll
      for (int ks = 0; ks < 2; ++ks) {
        int rA = wr + mi * 16 + (lane & 15);
        int rB = wc + mi * 16 + (lane & 15);
        int g = ks * 4 + (lane >> 4);
        af[mi][ks]  = *(const bf16x8v*)&sA[rA * 64 + ((g ^ (rA & 7)) * 8)];
        bfr[mi][ks] = *(const bf16x8v*)&sB[rB * 64 + ((g ^ (rB & 7)) * 8)];
      }
#pragma unroll
    for (int ks = 0; ks < 2; ++ks)
#pragma unroll
      for (int mi = 0; mi < 4; ++mi)
#pragma unroll
        for (int ni = 0; ni < 4; ++ni)
          acc[mi][ni] = MFMA16(af[mi][ks], bfr[ni][ks], acc[mi][ni]);
    __syncthreads();
  }

  const int rb = (lane >> 4) * 4, cb = lane & 15;
  if constexpr (MODE == 0 || MODE == 1) {
    bf16* C = (bf16*)Cv + cStr * bz;
#pragma unroll
    for (int mi = 0; mi < 4; ++mi)
#pragma unroll
      for (int ni = 0; ni < 4; ++ni) {
        int r0 = bm + wr + mi * 16 + rb, c0 = bn + wc + ni * 16 + cb;
#pragma unroll
        for (int k = 0; k < 4; ++k)
          C[(long)(r0 + k) * ldC + c0] = __float2bfloat16(acc[mi][ni][k]);
      }
  } else {
    float* C = (float*)Cv + cStr * bz;
#pragma unroll
    for (int mi = 0; mi < 4; ++mi)
#pragma unroll
      for (int ni = 0; ni < 4; ++ni) {
        int r0 = bm + wr + mi * 16 + rb, c0 = bn + wc + ni * 16 + cb;
#pragma unroll
        for (int k = 0; k < 4; ++k) {
          int r = r0 + k;
          C[(long)r * ldC + c0] = acc[mi][ni][k] + bias[r];
        }
      }
  }

  if constexpr (MODE == 0) {
    // per-column (over this block's 128 rows) online-softmax partials (exact fp32)
    float cm[4], cs[4];
#pragma unroll
    for (int ni = 0; ni < 4; ++ni) {
      float m = -3.0e38f;
#pragma unroll
      for (int mi = 0; mi < 4; ++mi)
#pragma unroll
        for (int k = 0; k < 4; ++k) m = fmaxf(m, acc[mi][ni][k]);
      float s = 0.f;
#pragma unroll
      for (int mi = 0; mi < 4; ++mi)
#pragma unroll
        for (int k = 0; k < 4; ++k) s += __expf(acc[mi][ni][k] - m);
#pragma unroll
      for (int off = 16; off <= 32; off <<= 1) {
        float mo = __shfl_xor(m, off, 64);
        float so = __shfl_xor(s, off, 64);
        float M = fmaxf(m, mo);
        s = s * __expf(m - M) + so * __expf(mo - M);
        m = M;
      }
      cm[ni] = m; cs[ni] = s;
    }
    __syncthreads();  // LDS reads of K-loop complete; reuse smx/ssx safely
    if (lane < 16) {
#pragma unroll
      for (int ni = 0; ni < 4; ++ni) {
        smx[wv][ni * 16 + lane] = cm[ni];
        ssx[wv][ni * 16 + lane] = cs[ni];
      }
    }
    __syncthreads();
    if (tid < 128) {
      int half = tid >> 6, c64 = tid & 63;
      float m1 = smx[half][c64], s1 = ssx[half][c64];
      float m2 = smx[half + 2][c64], s2 = ssx[half + 2][c64];
      float M = fmaxf(m1, m2);
      float S = s1 * __expf(m1 - M) + s2 * __expf(m2 - M);
      long o = ((long)bz * 16 + by) * NPT + bn + half * 64 + c64;
      PMo[o] = M;
      PSo[o] = S;
    }
  }
}

// ---- combine 16 partials per column -> CM, CSi ----
__global__ void k_cms_fin(const float* __restrict__ PM, const float* __restrict__ PS,
                          float* __restrict__ CM, float* __restrict__ CSi) {
  long idx = (long)blockIdx.x * 256 + threadIdx.x;  // [G*NPT]
  long z = idx >> 11;
  int n = idx & (NPT - 1);
  const float* pm = PM + z * 16 * NPT + n;
  const float* ps = PS + z * 16 * NPT + n;
  float m = -3.0e38f;
#pragma unroll
  for (int y = 0; y < 16; ++y) m = fmaxf(m, pm[(long)y * NPT]);
  float s = 0.f;
#pragma unroll
  for (int y = 0; y < 16; ++y) s += ps[(long)y * NPT] * __expf(pm[(long)y * NPT] - m);
  CM[idx] = m;
  CSi[idx] = 1.0f / s;
}

// ---- fused normalize + rowsum + V.P GEMM (F bf16, 2-phase dbuf, 8 waves) ----
// Per block: e = 0..255 (M), m in [m0, m0+64) (N), K = n = 0..2047.
// 512 threads = 8 waves arranged 4(e) x 2(m); tile 256e x 64m.
// 1-D grid 32*nz; z = bid % nz pins each batch's V to one XCD's L2.
// CM/CSi staged once in LDS. Per-step sync: counted s_waitcnt vmcnt(1) +
// lgkmcnt(0) + raw s_barrier. Issue order per step = STAGEV(4) then LOADF(1),
// so vmcnt(1) retires the 4 stage loads (oldest) while the F prefetch stays
// in flight across the barrier. Every step issues exactly 5 vmem ops
// (STAGEV/LOADF unconditional with column wrap).
__global__ __launch_bounds__(512) void k_vp(const bf16* __restrict__ F,
                                            const float* __restrict__ CM,
                                            const float* __restrict__ CSi,
                                            const bf16* __restrict__ V,
                                            float* __restrict__ H, int nz) {
  __shared__ __align__(16) bf16 sA[2][256 * 64];  // V tiles (double-buffered)
  __shared__ __align__(16) bf16 sB[2][64 * 64];   // PT tiles (double-buffered)
  __shared__ float rsLds[64][8];
  __shared__ float Sv[64];
  __shared__ float smCM[NPT], smCS[NPT];
  const int z = blockIdx.x % nz;
  const int m0 = (blockIdx.x / nz) * 64;
  const int tid = threadIdx.x;
  const int lane = tid & 63, wv = tid >> 6;
  const int we = wv & 3;   // e-quarter 0..3 (64 rows)
  const int wm = wv >> 2;  // m-half 0..1 (32 cols)
  const int fr = tid >> 3; // F row 0..63
  const int fq = tid & 7;  // F col chunk 0..7
  const bf16* Vz = V + (long)z * STRD;
  const bf16* Frp = F + (long)z * NN + (long)(m0 + fr) * NPT + fq * 8;
  f32x4 acc[4][2] = {};
  float rs = 0.f;
  bf16x8v fvA, fvB;

  // one-time: stage CM/CSi for this batch into LDS (16 KB)
  {
    const float* cmz = CM + (long)z * NPT;
    const float* csz = CSi + (long)z * NPT;
#pragma unroll
    for (int i = 0; i < 4; ++i) {
      int idx = i * 512 + tid;
      smCM[idx] = cmz[idx];
      smCS[idx] = csz[idx];
    }
  }

#define LOADF(FREG, N0) FREG = *(const bf16x8v*)(Frp + ((N0) & 2047));

  // EXPW: exp of register F chunk (scales from LDS) -> sB[buf]; accumulate rs
#define EXPW(BUF, FREG, N0)                                                    \
  {                                                                            \
    float mv[8], cv[8];                                                        \
    *(float4*)&mv[0] = *(const float4*)&smCM[(N0) + fq * 8];                   \
    *(float4*)&mv[4] = *(const float4*)&smCM[(N0) + fq * 8 + 4];               \
    *(float4*)&cv[0] = *(const float4*)&smCS[(N0) + fq * 8];                   \
    *(float4*)&cv[4] = *(const float4*)&smCS[(N0) + fq * 8 + 4];               \
    bf16 tb[8];                                                                \
    _Pragma("unroll") for (int i = 0; i < 8; ++i) {                            \
      float fvi = __uint_as_float((unsigned)(unsigned short)FREG[i] << 16);    \
      float pv = __expf(fvi - mv[i]) * cv[i];                                  \
      rs += pv;                                                                \
      tb[i] = __float2bfloat16(pv);                                            \
    }                                                                          \
    *(bf16x8v*)&sB[BUF][fr * 64 + ((fq ^ (fr & 7)) * 8)] = *(bf16x8v*)tb;      \
  }

  // STAGEV: issue 4 global_load_lds of V column-chunk into sA[buf] (512 thr)
#define STAGEV(BUF, N0)                                                        \
  _Pragma("unroll") for (int i = 0; i < 4; ++i) {                              \
    int c = i * 512 + tid;                                                     \
    int row = c >> 3, g = c & 7;                                               \
    gload16(Vz + (long)row * NPT + ((N0) & 2047) + ((g ^ (row & 7)) * 8),      \
            &sA[BUF][c * 8]);                                                  \
  }

  // counted-vmcnt step sync: stage loads (oldest 4 of 5) must land; the F
  // prefetch (newest) stays outstanding across the barrier.
#define WAITBAR                                                                \
  asm volatile("s_waitcnt vmcnt(1) lgkmcnt(0)" ::: "memory");                  \
  __builtin_amdgcn_s_barrier();

  // prologue
  LOADF(fvA, 0)
  STAGEV(0, 0)
  __syncthreads();  // scales in LDS visible; V(0) + F(0) drained
  EXPW(0, fvA, 0)
  LOADF(fvB, 64)
  __syncthreads();  // PT(0) visible; F(1) drained

  // body: stage V(step+1); prefetch F(step+2); exp PT(step+1); MFMA(step);
  // counted-vmcnt barrier.
#define VP_BODY(CUR, FN, FN2, STEPI)                                           \
  {                                                                            \
    const int sn = (STEPI);                                                    \
    const int nn0 = sn * 64;                                                   \
    STAGEV(CUR ^ 1, nn0 + 64)                                                  \
    LOADF(FN2, nn0 + 128)                                                      \
    if (sn + 1 < 32) EXPW(CUR ^ 1, FN, nn0 + 64)                               \
    bf16x8v bfr[2][2];                                                         \
    _Pragma("unroll") for (int ni = 0; ni < 2; ++ni)                           \
      _Pragma("unroll") for (int ks = 0; ks < 2; ++ks) {                       \
        int rB = wm * 32 + ni * 16 + (lane & 15);                              \
        int g = ks * 4 + (lane >> 4);                                          \
        bfr[ni][ks] = *(const bf16x8v*)&sB[CUR][rB * 64 + ((g ^ (rB & 7)) * 8)]; \
      }                                                                        \
    _Pragma("unroll") for (int mi = 0; mi < 4; ++mi)                           \
      _Pragma("unroll") for (int ks = 0; ks < 2; ++ks) {                       \
        int rA = we * 64 + mi * 16 + (lane & 15);                              \
        int g = ks * 4 + (lane >> 4);                                          \
        bf16x8v af = *(const bf16x8v*)&sA[CUR][rA * 64 + ((g ^ (rA & 7)) * 8)]; \
        _Pragma("unroll") for (int ni = 0; ni < 2; ++ni)                       \
          acc[mi][ni] = MFMA16(af, bfr[ni][ks], acc[mi][ni]);                  \
      }                                                                        \
    WAITBAR                                                                    \
  }

  for (int it = 0; it < 16; ++it) {
    VP_BODY(0, fvB, fvA, 2 * it)
    VP_BODY(1, fvA, fvB, 2 * it + 1)
  }
#undef VP_BODY
#undef WAITBAR
#undef STAGEV
#undef EXPW
#undef LOADF

  rsLds[fr][fq] = rs;
  __syncthreads();
  if (tid < 64) {
    float R = 0.f;
#pragma unroll
    for (int q = 0; q < 8; ++q) R += rsLds[tid][q];
    Sv[tid] = 1.0f / (1e-9f + R);
  }
  __syncthreads();

  float* Hz = H + (long)z * STRD;
  const int rb = (lane >> 4) * 4, cb = lane & 15;
#pragma unroll
  for (int mi = 0; mi < 4; ++mi) {
    int e0 = we * 64 + mi * 16 + rb;
#pragma unroll
    for (int ni = 0; ni < 2; ++ni) {
      int c = wm * 32 + ni * 16 + cb;
      float scl = Sv[c];
#pragma unroll
      for (int k = 0; k < 4; ++k)
        Hz[(long)(e0 + k) * NPT + m0 + c] += acc[mi][ni][k] * scl;
    }
  }
}

// ---- pooled[b,n] = mean over e of H[b,e,n] ----
__global__ void k_pool(const float* __restrict__ H, float* __restrict__ pooled) {
  int i = blockIdx.x * 256 + threadIdx.x;
  if (i >= BATCH * NPT) return;
  int b = i >> 11, n = i & (NPT - 1);
  const float* p = H + (long)b * STRD + n;
  float s = 0.f;
  for (int e = 0; e < DEMB; ++e) s += p[(long)e * NPT];
  pooled[i] = s * (1.0f / DEMB);
}

// ---- fc1: one block per output row j; w row read ONCE, all 8 batches ----
__global__ __launch_bounds__(256) void k_fc1(const float* __restrict__ pooled,
                                             const float* __restrict__ w, const float* __restrict__ bias,
                                             float* __restrict__ f) {
  int j = blockIdx.x;
  const float* wr = w + (long)j * NPT;
  int n0 = threadIdx.x * 8;
  float wl[8];
  *(float4*)&wl[0] = *(const float4*)(wr + n0);
  *(float4*)&wl[4] = *(const float4*)(wr + n0 + 4);
  float part[8];
#pragma unroll
  for (int b = 0; b < 8; ++b) {
    const float* pp = pooled + (long)b * NPT + n0;
    float4 p0 = *(const float4*)pp, p1 = *(const float4*)(pp + 4);
    part[b] = wl[0] * p0.x + wl[1] * p0.y + wl[2] * p0.z + wl[3] * p0.w +
              wl[4] * p1.x + wl[5] * p1.y + wl[6] * p1.z + wl[7] * p1.w;
  }
#pragma unroll
  for (int b = 0; b < 8; ++b) {
    float s = blockReduceSum(part[b]);
    if (threadIdx.x == 0) {
      s += bias[j];
      f[(long)b * NPT + j] = s > 0.f ? s : 0.f;
    }
  }
}

// ---- fc2 ----
__global__ __launch_bounds__(256) void k_fc2(const float* __restrict__ f,
                                             const float* __restrict__ w, const float* __restrict__ bias,
                                             float* __restrict__ out) {
  int b = blockIdx.x;
  float s = 0.f;
  for (int j = threadIdx.x; j < NPT; j += 256) s += f[(long)b * NPT + j] * w[j];
  s = blockReduceSum(s);
  if (threadIdx.x == 0) out[b] = s + bias[0];
}

extern "C" void kernel_launch(void* const* d_in, const int* in_sizes, int n_in,
                              void* d_out, int out_size, void* d_ws, size_t ws_size,
                              hipStream_t stream) {
  const float* X    = (const float*)d_in[0];
  const float* W1   = (const float*)d_in[1];
  const float* B1   = (const float*)d_in[2];
  const float* G1   = (const float*)d_in[3];
  const float* BE1  = (const float*)d_in[4];
  const float* W2   = (const float*)d_in[5];
  const float* B2   = (const float*)d_in[6];
  const float* G2   = (const float*)d_in[7];
  const float* BE2  = (const float*)d_in[8];
  const float* WQ   = (const float*)d_in[9];
  const float* WK   = (const float*)d_in[10];
  const float* WV   = (const float*)d_in[11];
  const float* FC1W = (const float*)d_in[12];
  const float* FC1B = (const float*)d_in[13];
  const float* FC2W = (const float*)d_in[14];
  const float* FC2B = (const float*)d_in[15];
  float* OUT = (float*)d_out;

  // ---- workspace carve-out ----
  char* p = (char*)d_ws;
  auto alloc = [&](size_t bytes) -> char* {
    char* r = p;
    p += (bytes + 255) & ~(size_t)255;
    return r;
  };
  float* H1t  = (float*)alloc((size_t)BATCH * NPT * DMID * 4);
  bf16*  H1tb = (bf16*)alloc((size_t)BATCH * NPT * DMID * 2);
  float* H    = (float*)alloc((size_t)BATCH * STRD * 4);
  bf16*  Ht   = (bf16*)alloc((size_t)BATCH * STRD * 2);
  bf16*  QKt  = (bf16*)alloc((size_t)BATCH * QKS * 2);   // [b][n][512] = Q(0..255) | K(256..511)
  bf16*  Vb   = (bf16*)alloc((size_t)BATCH * STRD * 2);
  bf16*  W2b  = (bf16*)alloc((size_t)DEMB * DMID * 2);
  bf16*  WQKb = (bf16*)alloc((size_t)NSA * 512 * DEMB * 2);
  bf16*  WVb  = (bf16*)alloc((size_t)NSA * DEMB * DEMB * 2);
  float* pS   = (float*)alloc(128 * 64 * 4);
  float* pS2  = (float*)alloc(128 * 64 * 4);
  float* sa1  = (float*)alloc(64 * 4);
  float* sb1  = (float*)alloc(64 * 4);
  float* sa2  = (float*)alloc(256 * 4);
  float* sb2  = (float*)alloc(256 * 4);
  float* CM   = (float*)alloc((size_t)BATCH * NPT * 4);
  float* CSi  = (float*)alloc((size_t)BATCH * NPT * 4);
  float* PM   = (float*)alloc((size_t)BATCH * 16 * NPT * 4);
  float* PSm  = (float*)alloc((size_t)BATCH * 16 * NPT * 4);
  float* POOL = (float*)alloc((size_t)BATCH * NPT * 4);
  float* FH   = (float*)alloc((size_t)BATCH * NPT * 4);
  size_t used = (size_t)(p - (char*)d_ws);
  const size_t per_g = (size_t)NN * 2;  // F bf16 (8MB per batch)
  int G = 8;
  while (G > 1 && used + (size_t)G * per_g + 1024 > ws_size) G >>= 1;
  bf16* F = (bf16*)alloc((size_t)G * NN * 2);

  // ---- weight converts ----
  k_cvt<<<(DEMB * DMID + 255) / 256, 256, 0, stream>>>(W2, W2b, DEMB * DMID);
  int nqk = NSA * 512 * DEMB;
  k_cvtqk<<<nqk / 256, 256, 0, stream>>>(WQ, WK, WQKb);
  int nw = NSA * DEMB * DEMB;
  k_cvt<<<(nw + 255) / 256, 256, 0, stream>>>(WV, WVb, nw);

  // ---- conv1 + BN1 + ReLU (-> H1tb bf16 [b][n][64]) ----
  long szh1 = (long)BATCH * NPT * DMID;
  k_conv1t<<<(int)(szh1 / 256), 256, 0, stream>>>(X, W1, B1, H1t);
  k_bn1a<<<128, 256, 0, stream>>>(H1t, pS, pS2);
  k_bn1b<<<1, 64, 0, stream>>>(pS, pS2, G1, BE1, sa1, sb1);
  k_bn1apply<<<(int)(szh1 / 256), 256, 0, stream>>>(H1t, sa1, sb1, H1tb);

  // ---- conv2 (MFMA) + BN2 + ReLU -> H fp32 [b][256][2048] ----
  k_mgemm<2><<<dim3(16, 2, 8), 256, 0, stream>>>(W2b, 0, DMID, H1tb, (long)NPT * DMID, DMID,
                                                 H, STRD, NPT, DMID, B2, nullptr, nullptr, 0);
  k_bnstats<<<DEMB, 256, 0, stream>>>(H, DEMB, G2, BE2, sa2, sb2);
  k_bnapply<<<(int)(BATCH * STRD / 256), 256, 0, stream>>>(H, sa2, sb2, DEMB, (int)(BATCH * STRD));

  // ---- SA layers ----
  for (int l = 0; l < NSA; ++l) {
    k_tcvt<<<dim3(32, 4, 8), 256, 0, stream>>>(H, Ht);
    // QKt[n][0..511] = Ht . [Wq;Wk]^T  : A=Ht (M=2048), B=WQK (N=512)
    k_mgemm<1><<<dim3(4, 16, 8), 256, 0, stream>>>(Ht, STRD, DEMB, WQKb + (long)l * 512 * DEMB, 0, DEMB,
                                                   QKt, QKS, 512, DEMB, nullptr, nullptr, nullptr, 0);
    // V[e][n] : A=Wv (M=256), B=Ht (N=2048)
    k_mgemm<1><<<dim3(16, 2, 8), 256, 0, stream>>>(WVb + (long)l * DEMB * DEMB, 0, DEMB, Ht, STRD, DEMB,
                                                   Vb, STRD, NPT, DEMB, nullptr, nullptr, nullptr, 0);
    for (int b0 = 0; b0 < BATCH; b0 += G) {
      // F[m][n] = sum_a Kt[m][a] Qt[n][a] (= E^T), bf16 + fused exact column stats
      // 1-D grid, z = bid % G pins each batch's QKt panels to one XCD's L2
      k_mgemm<0><<<dim3(256 * G), 256, 0, stream>>>(QKt + 256 + b0 * QKS, QKS, 512,
                                                    QKt + b0 * QKS, QKS, 512,
                                                    F, NN, NPT, DEMB, nullptr, PM, PSm, G);
      k_cms_fin<<<G * NPT / 256, 256, 0, stream>>>(PM, PSm, CM, CSi);
      // H[e][m] += S[m] * sum_n V[e][n] PT[m][n]  (PT from bf16 F on the fly)
      k_vp<<<dim3(32 * G), 512, 0, stream>>>(F, CM, CSi, Vb + b0 * STRD, H + b0 * STRD, G);
    }
  }

  // ---- head ----
  k_pool<<<(BATCH * NPT) / 256, 256, 0, stream>>>(H, POOL);
  k_fc1<<<NPT, 256, 0, stream>>>(POOL, FC1W, FC1B, FH);
  k_fc2<<<BATCH, 256, 0, stream>>>(FH, FC2W, FC2B, OUT);
}

// Round 15
// 433.510 us; speedup vs baseline: 1.1137x; 1.0650x over previous
//
#include <hip/hip_runtime.h>
#include <hip/hip_bf16.h>

typedef __hip_bfloat16 bf16;
#define DEVI __device__ __forceinline__

// Problem constants
static constexpr int BATCH = 8;
static constexpr int NPT   = 2048;
static constexpr int DMID  = 64;
static constexpr int DEMB  = 256;
static constexpr int NSA   = 4;
static constexpr long STRD = (long)DEMB * NPT;  // 524288
static constexpr long QKS  = (long)NPT * 512;   // per-batch stride of QKt
static constexpr long NN   = (long)NPT * NPT;   // 4194304

typedef __attribute__((ext_vector_type(4))) float f32x4;
typedef __attribute__((ext_vector_type(8))) short bf16x8v;

DEVI f32x4 MFMA16(bf16x8v a, bf16x8v b, f32x4 c) {
  return __builtin_amdgcn_mfma_f32_16x16x32_bf16(a, b, c, 0, 0, 0);
}

DEVI void gload16(const bf16* g, bf16* l) {
  __builtin_amdgcn_global_load_lds(
      (const __attribute__((address_space(1))) void*)g,
      (__attribute__((address_space(3))) void*)l, 16, 0, 0);
}

DEVI float waveReduceSum(float v) {
#pragma unroll
  for (int o = 32; o > 0; o >>= 1) v += __shfl_down(v, o, 64);
  return v;
}
DEVI float blockReduceSum(float v) {
  __shared__ float sm[4];
  int lane = threadIdx.x & 63, wid = threadIdx.x >> 6;
  __syncthreads();
  v = waveReduceSum(v);
  if (lane == 0) sm[wid] = v;
  __syncthreads();
  return sm[0] + sm[1] + sm[2] + sm[3];
}

// ---- fp32 -> bf16 convert ----
__global__ void k_cvt(const float* __restrict__ in, bf16* __restrict__ out, int n) {
  int i = blockIdx.x * 256 + threadIdx.x;
  if (i < n) out[i] = __float2bfloat16(in[i]);
}

// ---- concat-convert Wq,Wk -> WQKb [l][512][256] bf16 ----
__global__ void k_cvtqk(const float* __restrict__ wq, const float* __restrict__ wk,
                        bf16* __restrict__ o) {
  int idx = blockIdx.x * 256 + threadIdx.x;  // NSA*512*256
  int c = idx & 255;
  int r = (idx >> 8) & 511;
  int l = idx >> 17;
  float v = (r < 256) ? wq[((l << 8) + r) * 256 + c] : wk[((l << 8) + (r - 256)) * 256 + c];
  o[idx] = __float2bfloat16(v);
}

// ---- conv1: H1t[b][n][o] = sum_c x[b,n,c]*w1[o,c] + b1[o] ----
__global__ void k_conv1t(const float* __restrict__ x, const float* __restrict__ w1,
                         const float* __restrict__ b1, float* __restrict__ h1t) {
  long idx = (long)blockIdx.x * 256 + threadIdx.x;  // [b*n][o]
  int o = idx & 63;
  long bn = idx >> 6;
  const float* xp = x + bn * 3;
  h1t[idx] = b1[o] + xp[0] * w1[o * 3] + xp[1] * w1[o * 3 + 1] + xp[2] * w1[o * 3 + 2];
}

// ---- BN1 stats on H1t [16384][64] ----
__global__ __launch_bounds__(256) void k_bn1a(const float* __restrict__ h, float* __restrict__ pS,
                                              float* __restrict__ pS2) {
  int c = threadIdx.x & 63, rg = threadIdx.x >> 6;
  long r0 = (long)blockIdx.x * 128 + rg * 32;
  float s = 0.f, s2 = 0.f;
  for (int i = 0; i < 32; ++i) {
    float v = h[(r0 + i) * 64 + c];
    s += v; s2 += v * v;
  }
  __shared__ float smS[256], smS2[256];
  smS[threadIdx.x] = s; smS2[threadIdx.x] = s2;
  __syncthreads();
  if (threadIdx.x < 64) {
    float a = 0.f, b = 0.f;
#pragma unroll
    for (int g = 0; g < 4; ++g) { a += smS[g * 64 + c]; b += smS2[g * 64 + c]; }
    pS[blockIdx.x * 64 + c] = a;
    pS2[blockIdx.x * 64 + c] = b;
  }
}
__global__ void k_bn1b(const float* __restrict__ pS, const float* __restrict__ pS2,
                       const float* __restrict__ g, const float* __restrict__ be,
                       float* __restrict__ sa, float* __restrict__ sb) {
  int c = threadIdx.x;
  if (c >= 64) return;
  float s = 0.f, s2 = 0.f;
  for (int i = 0; i < 128; ++i) { s += pS[i * 64 + c]; s2 += pS2[i * 64 + c]; }
  const float inv = 1.0f / (BATCH * NPT);
  float m = s * inv, var = s2 * inv - m * m;
  float A = rsqrtf(var + 1e-5f) * g[c];
  sa[c] = A; sb[c] = be[c] - m * A;
}
__global__ void k_bn1apply(const float* __restrict__ h, const float* __restrict__ sa,
                           const float* __restrict__ sb, bf16* __restrict__ o) {
  long idx = (long)blockIdx.x * 256 + threadIdx.x;
  int c = idx & 63;
  float v = fmaf(h[idx], sa[c], sb[c]);
  o[idx] = __float2bfloat16(v > 0.f ? v : 0.f);
}

// ---- BN2 stats on Hn [16384][256] (per-column = per-channel) ----
__global__ __launch_bounds__(256) void k_bn2a(const float* __restrict__ h,
                                              float* __restrict__ pA, float* __restrict__ pB) {
  int c = threadIdx.x;
  long r0 = (long)blockIdx.x * 128;
  float s = 0.f, s2 = 0.f;
  for (int i = 0; i < 128; ++i) {
    float v = h[(r0 + i) * DEMB + c];
    s += v; s2 += v * v;
  }
  pA[blockIdx.x * DEMB + c] = s;
  pB[blockIdx.x * DEMB + c] = s2;
}
__global__ void k_bn2b(const float* __restrict__ pA, const float* __restrict__ pB,
                       const float* __restrict__ g, const float* __restrict__ be,
                       float* __restrict__ sa, float* __restrict__ sb) {
  int c = threadIdx.x;  // 256 threads
  float s = 0.f, s2 = 0.f;
  for (int i = 0; i < 128; ++i) { s += pA[i * DEMB + c]; s2 += pB[i * DEMB + c]; }
  const float inv = 1.0f / (BATCH * NPT);
  float m = s * inv, var = s2 * inv - m * m;
  float A = rsqrtf(var + 1e-5f) * g[c];
  sa[c] = A; sb[c] = be[c] - m * A;
}
// BN2 apply + ReLU: write Hn (f32 residual) and Htb (bf16 operand)
__global__ void k_bnapply2(float* __restrict__ hn, bf16* __restrict__ htb,
                           const float* __restrict__ sa, const float* __restrict__ sb) {
  long idx = (long)blockIdx.x * 256 + threadIdx.x;
  int c = idx & (DEMB - 1);
  float v = fmaf(hn[idx], sa[c], sb[c]);
  v = v > 0.f ? v : 0.f;
  hn[idx] = v;
  htb[idx] = __float2bfloat16(v);
}

// ---- MFMA GEMM, B^T form: C[M][N] = A[M][K] . B[N][K]^T ; 128x128 tile, BK=64 ----
// XOR-swizzled LDS (granule ^= row&7) on both staging-source and read.
// MODE 0: C bf16 = acc + fused column-softmax partials; 1-D grid, z = bid % nz (XCD-pin)
// MODE 1: C bf16 = acc
// MODE 2: C f32 = acc + bias[col]
template <int MODE>
__global__ __launch_bounds__(256) void k_mgemm(
    const bf16* __restrict__ A, long aStr, int ldA,
    const bf16* __restrict__ B, long bStr, int ldB,
    void* __restrict__ Cv, long cStr, int ldC,
    int K,
    const float* __restrict__ bias,
    float* __restrict__ PMo, float* __restrict__ PSo, int nz) {
  __shared__ __align__(16) bf16 sA[128 * 64];
  __shared__ __align__(16) bf16 sB[128 * 64];
  __shared__ float smx[4][64], ssx[4][64];
  int bx, by, bz;
  if constexpr (MODE == 0) {
    bz = blockIdx.x % nz;
    int t = blockIdx.x / nz;
    bx = t & 15;
    by = t >> 4;
  } else {
    bx = blockIdx.x; by = blockIdx.y; bz = blockIdx.z;
  }
  A += aStr * bz;
  B += bStr * bz;
  const int bm = by * 128, bn = bx * 128;
  const int tid = threadIdx.x;
  const int lane = tid & 63, wv = tid >> 6;
  const int wr = (wv >> 1) * 64, wc = (wv & 1) * 64;
  f32x4 acc[4][4] = {};

  for (int k0 = 0; k0 < K; k0 += 64) {
#pragma unroll
    for (int i = 0; i < 4; ++i) {
      int c = i * 256 + tid;
      int row = c >> 3, g = c & 7;
      int gs = (g ^ (row & 7)) * 8;
      gload16(A + (long)(bm + row) * ldA + k0 + gs, sA + c * 8);
      gload16(B + (long)(bn + row) * ldB + k0 + gs, sB + c * 8);
    }
    __syncthreads();
    bf16x8v af[4][2], bfr[4][2];
#pragma unroll
    for (int mi = 0; mi < 4; ++mi)
#pragma unroll
      for (int ks = 0; ks < 2; ++ks) {
        int rA = wr + mi * 16 + (lane & 15);
        int rB = wc + mi * 16 + (lane & 15);
        int g = ks * 4 + (lane >> 4);
        af[mi][ks]  = *(const bf16x8v*)&sA[rA * 64 + ((g ^ (rA & 7)) * 8)];
        bfr[mi][ks] = *(const bf16x8v*)&sB[rB * 64 + ((g ^ (rB & 7)) * 8)];
      }
#pragma unroll
    for (int ks = 0; ks < 2; ++ks)
#pragma unroll
      for (int mi = 0; mi < 4; ++mi)
#pragma unroll
        for (int ni = 0; ni < 4; ++ni)
          acc[mi][ni] = MFMA16(af[mi][ks], bfr[ni][ks], acc[mi][ni]);
    __syncthreads();
  }

  const int rb = (lane >> 4) * 4, cb = lane & 15;
  if constexpr (MODE == 0 || MODE == 1) {
    bf16* C = (bf16*)Cv + cStr * bz;
#pragma unroll
    for (int mi = 0; mi < 4; ++mi)
#pragma unroll
      for (int ni = 0; ni < 4; ++ni) {
        int r0 = bm + wr + mi * 16 + rb, c0 = bn + wc + ni * 16 + cb;
#pragma unroll
        for (int k = 0; k < 4; ++k)
          C[(long)(r0 + k) * ldC + c0] = __float2bfloat16(acc[mi][ni][k]);
      }
  } else {
    float* C = (float*)Cv + cStr * bz;
#pragma unroll
    for (int mi = 0; mi < 4; ++mi)
#pragma unroll
      for (int ni = 0; ni < 4; ++ni) {
        int r0 = bm + wr + mi * 16 + rb, c0 = bn + wc + ni * 16 + cb;
        float badd = bias[c0];
#pragma unroll
        for (int k = 0; k < 4; ++k) {
          int r = r0 + k;
          C[(long)r * ldC + c0] = acc[mi][ni][k] + badd;
        }
      }
  }

  if constexpr (MODE == 0) {
    // per-column (over this block's 128 rows) online-softmax partials (exact fp32)
    float cm[4], cs[4];
#pragma unroll
    for (int ni = 0; ni < 4; ++ni) {
      float m = -3.0e38f;
#pragma unroll
      for (int mi = 0; mi < 4; ++mi)
#pragma unroll
        for (int k = 0; k < 4; ++k) m = fmaxf(m, acc[mi][ni][k]);
      float s = 0.f;
#pragma unroll
      for (int mi = 0; mi < 4; ++mi)
#pragma unroll
        for (int k = 0; k < 4; ++k) s += __expf(acc[mi][ni][k] - m);
#pragma unroll
      for (int off = 16; off <= 32; off <<= 1) {
        float mo = __shfl_xor(m, off, 64);
        float so = __shfl_xor(s, off, 64);
        float M = fmaxf(m, mo);
        s = s * __expf(m - M) + so * __expf(mo - M);
        m = M;
      }
      cm[ni] = m; cs[ni] = s;
    }
    __syncthreads();  // LDS reads of K-loop complete; reuse smx/ssx safely
    if (lane < 16) {
#pragma unroll
      for (int ni = 0; ni < 4; ++ni) {
        smx[wv][ni * 16 + lane] = cm[ni];
        ssx[wv][ni * 16 + lane] = cs[ni];
      }
    }
    __syncthreads();
    if (tid < 128) {
      int half = tid >> 6, c64 = tid & 63;
      float m1 = smx[half][c64], s1 = ssx[half][c64];
      float m2 = smx[half + 2][c64], s2 = ssx[half + 2][c64];
      float M = fmaxf(m1, m2);
      float S = s1 * __expf(m1 - M) + s2 * __expf(m2 - M);
      long o = ((long)bz * 16 + by) * NPT + bn + half * 64 + c64;
      PMo[o] = M;
      PSo[o] = S;
    }
  }
}

// ---- combine 16 partials per column -> CM, CSi ----
__global__ void k_cms_fin(const float* __restrict__ PM, const float* __restrict__ PS,
                          float* __restrict__ CM, float* __restrict__ CSi) {
  long idx = (long)blockIdx.x * 256 + threadIdx.x;  // [G*NPT]
  long z = idx >> 11;
  int n = idx & (NPT - 1);
  const float* pm = PM + z * 16 * NPT + n;
  const float* ps = PS + z * 16 * NPT + n;
  float m = -3.0e38f;
#pragma unroll
  for (int y = 0; y < 16; ++y) m = fmaxf(m, pm[(long)y * NPT]);
  float s = 0.f;
#pragma unroll
  for (int y = 0; y < 16; ++y) s += ps[(long)y * NPT] * __expf(pm[(long)y * NPT] - m);
  CM[idx] = m;
  CSi[idx] = 1.0f / s;
}

// ---- fused normalize + rowsum + V.P GEMM (F bf16, 2-phase dbuf, 8 waves) ----
// Per block: e = 0..255 (M), m in [m0, m0+64) (N), K = n = 0..2047.
// 512 threads = 8 waves arranged 4(e) x 2(m); tile 256e x 64m.
// 1-D grid 32*nz; z = bid % nz pins each batch's V to one XCD's L2.
// Epilogue: Hn[m][e] += acc*scl (f32 residual, [n][e] layout) AND
// Htb[m][e] = bf16(new) — fuses the next layer's operand convert.
// Per-step sync: counted s_waitcnt vmcnt(1)+lgkmcnt(0)+s_barrier; issue order
// STAGEV(4) then LOADF(1) keeps the F prefetch in flight across the barrier.
__global__ __launch_bounds__(512) void k_vp(const bf16* __restrict__ F,
                                            const float* __restrict__ CM,
                                            const float* __restrict__ CSi,
                                            const bf16* __restrict__ V,
                                            float* __restrict__ Hn,
                                            bf16* __restrict__ Htb, int nz) {
  __shared__ __align__(16) bf16 sA[2][256 * 64];  // V tiles (double-buffered)
  __shared__ __align__(16) bf16 sB[2][64 * 64];   // PT tiles (double-buffered)
  __shared__ float rsLds[64][8];
  __shared__ float Sv[64];
  __shared__ float smCM[NPT], smCS[NPT];
  const int z = blockIdx.x % nz;
  const int m0 = (blockIdx.x / nz) * 64;
  const int tid = threadIdx.x;
  const int lane = tid & 63, wv = tid >> 6;
  const int we = wv & 3;   // e-quarter 0..3 (64 rows)
  const int wm = wv >> 2;  // m-half 0..1 (32 cols)
  const int fr = tid >> 3; // F row 0..63
  const int fq = tid & 7;  // F col chunk 0..7
  const bf16* Vz = V + (long)z * STRD;
  const bf16* Frp = F + (long)z * NN + (long)(m0 + fr) * NPT + fq * 8;
  f32x4 acc[4][2] = {};
  float rs = 0.f;
  bf16x8v fvA, fvB;

  // one-time: stage CM/CSi for this batch into LDS (16 KB)
  {
    const float* cmz = CM + (long)z * NPT;
    const float* csz = CSi + (long)z * NPT;
#pragma unroll
    for (int i = 0; i < 4; ++i) {
      int idx = i * 512 + tid;
      smCM[idx] = cmz[idx];
      smCS[idx] = csz[idx];
    }
  }

#define LOADF(FREG, N0) FREG = *(const bf16x8v*)(Frp + ((N0) & 2047));

#define EXPW(BUF, FREG, N0)                                                    \
  {                                                                            \
    float mv[8], cv[8];                                                        \
    *(float4*)&mv[0] = *(const float4*)&smCM[(N0) + fq * 8];                   \
    *(float4*)&mv[4] = *(const float4*)&smCM[(N0) + fq * 8 + 4];               \
    *(float4*)&cv[0] = *(const float4*)&smCS[(N0) + fq * 8];                   \
    *(float4*)&cv[4] = *(const float4*)&smCS[(N0) + fq * 8 + 4];               \
    bf16 tb[8];                                                                \
    _Pragma("unroll") for (int i = 0; i < 8; ++i) {                            \
      float fvi = __uint_as_float((unsigned)(unsigned short)FREG[i] << 16);    \
      float pv = __expf(fvi - mv[i]) * cv[i];                                  \
      rs += pv;                                                                \
      tb[i] = __float2bfloat16(pv);                                            \
    }                                                                          \
    *(bf16x8v*)&sB[BUF][fr * 64 + ((fq ^ (fr & 7)) * 8)] = *(bf16x8v*)tb;      \
  }

#define STAGEV(BUF, N0)                                                        \
  _Pragma("unroll") for (int i = 0; i < 4; ++i) {                              \
    int c = i * 512 + tid;                                                     \
    int row = c >> 3, g = c & 7;                                               \
    gload16(Vz + (long)row * NPT + ((N0) & 2047) + ((g ^ (row & 7)) * 8),      \
            &sA[BUF][c * 8]);                                                  \
  }

#define WAITBAR                                                                \
  asm volatile("s_waitcnt vmcnt(1) lgkmcnt(0)" ::: "memory");                  \
  __builtin_amdgcn_s_barrier();

  // prologue
  LOADF(fvA, 0)
  STAGEV(0, 0)
  __syncthreads();  // scales in LDS visible; V(0) + F(0) drained
  EXPW(0, fvA, 0)
  LOADF(fvB, 64)
  __syncthreads();  // PT(0) visible; F(1) drained

#define VP_BODY(CUR, FN, FN2, STEPI)                                           \
  {                                                                            \
    const int sn = (STEPI);                                                    \
    const int nn0 = sn * 64;                                                   \
    STAGEV(CUR ^ 1, nn0 + 64)                                                  \
    LOADF(FN2, nn0 + 128)                                                      \
    if (sn + 1 < 32) EXPW(CUR ^ 1, FN, nn0 + 64)                               \
    bf16x8v bfr[2][2];                                                         \
    _Pragma("unroll") for (int ni = 0; ni < 2; ++ni)                           \
      _Pragma("unroll") for (int ks = 0; ks < 2; ++ks) {                       \
        int rB = wm * 32 + ni * 16 + (lane & 15);                              \
        int g = ks * 4 + (lane >> 4);                                          \
        bfr[ni][ks] = *(const bf16x8v*)&sB[CUR][rB * 64 + ((g ^ (rB & 7)) * 8)]; \
      }                                                                        \
    _Pragma("unroll") for (int mi = 0; mi < 4; ++mi)                           \
      _Pragma("unroll") for (int ks = 0; ks < 2; ++ks) {                       \
        int rA = we * 64 + mi * 16 + (lane & 15);                              \
        int g = ks * 4 + (lane >> 4);                                          \
        bf16x8v af = *(const bf16x8v*)&sA[CUR][rA * 64 + ((g ^ (rA & 7)) * 8)]; \
        _Pragma("unroll") for (int ni = 0; ni < 2; ++ni)                       \
          acc[mi][ni] = MFMA16(af, bfr[ni][ks], acc[mi][ni]);                  \
      }                                                                        \
    WAITBAR                                                                    \
  }

  for (int it = 0; it < 16; ++it) {
    VP_BODY(0, fvB, fvA, 2 * it)
    VP_BODY(1, fvA, fvB, 2 * it + 1)
  }
#undef VP_BODY
#undef WAITBAR
#undef STAGEV
#undef EXPW
#undef LOADF

  rsLds[fr][fq] = rs;
  __syncthreads();
  if (tid < 64) {
    float R = 0.f;
#pragma unroll
    for (int q = 0; q < 8; ++q) R += rsLds[tid][q];
    Sv[tid] = 1.0f / (1e-9f + R);
  }
  __syncthreads();

  float* Hz = Hn + (long)z * STRD;
  bf16* Hb = Htb + (long)z * STRD;
  const int rb = (lane >> 4) * 4, cb = lane & 15;
#pragma unroll
  for (int mi = 0; mi < 4; ++mi) {
    int e0 = we * 64 + mi * 16 + rb;
#pragma unroll
    for (int ni = 0; ni < 2; ++ni) {
      int c = wm * 32 + ni * 16 + cb;
      float scl = Sv[c];
      long base = (long)(m0 + c) * DEMB + e0;
      float4 h = *(const float4*)(Hz + base);
      float r0 = h.x + acc[mi][ni][0] * scl;
      float r1 = h.y + acc[mi][ni][1] * scl;
      float r2 = h.z + acc[mi][ni][2] * scl;
      float r3 = h.w + acc[mi][ni][3] * scl;
      *(float4*)(Hz + base) = float4{r0, r1, r2, r3};
      bf16 hb[4] = {__float2bfloat16(r0), __float2bfloat16(r1),
                    __float2bfloat16(r2), __float2bfloat16(r3)};
      *(uint2*)(Hb + base) = *(uint2*)hb;
    }
  }
}

// ---- pooled[b*n] = row mean of Hn [16384][256] (one wave per row) ----
__global__ void k_pool(const float* __restrict__ Hn, float* __restrict__ pooled) {
  int row = blockIdx.x * 4 + (threadIdx.x >> 6);
  int lane = threadIdx.x & 63;
  float4 v = *(const float4*)(Hn + (long)row * DEMB + lane * 4);
  float s = v.x + v.y + v.z + v.w;
  s = waveReduceSum(s);
  if (lane == 0) pooled[row] = s * (1.0f / DEMB);
}

// ---- fc1: one block per output row j; w row read ONCE, all 8 batches ----
__global__ __launch_bounds__(256) void k_fc1(const float* __restrict__ pooled,
                                             const float* __restrict__ w, const float* __restrict__ bias,
                                             float* __restrict__ f) {
  int j = blockIdx.x;
  const float* wr = w + (long)j * NPT;
  int n0 = threadIdx.x * 8;
  float wl[8];
  *(float4*)&wl[0] = *(const float4*)(wr + n0);
  *(float4*)&wl[4] = *(const float4*)(wr + n0 + 4);
  float part[8];
#pragma unroll
  for (int b = 0; b < 8; ++b) {
    const float* pp = pooled + (long)b * NPT + n0;
    float4 p0 = *(const float4*)pp, p1 = *(const float4*)(pp + 4);
    part[b] = wl[0] * p0.x + wl[1] * p0.y + wl[2] * p0.z + wl[3] * p0.w +
              wl[4] * p1.x + wl[5] * p1.y + wl[6] * p1.z + wl[7] * p1.w;
  }
#pragma unroll
  for (int b = 0; b < 8; ++b) {
    float s = blockReduceSum(part[b]);
    if (threadIdx.x == 0) {
      s += bias[j];
      f[(long)b * NPT + j] = s > 0.f ? s : 0.f;
    }
  }
}

// ---- fc2 ----
__global__ __launch_bounds__(256) void k_fc2(const float* __restrict__ f,
                                             const float* __restrict__ w, const float* __restrict__ bias,
                                             float* __restrict__ out) {
  int b = blockIdx.x;
  float s = 0.f;
  for (int j = threadIdx.x; j < NPT; j += 256) s += f[(long)b * NPT + j] * w[j];
  s = blockReduceSum(s);
  if (threadIdx.x == 0) out[b] = s + bias[0];
}

extern "C" void kernel_launch(void* const* d_in, const int* in_sizes, int n_in,
                              void* d_out, int out_size, void* d_ws, size_t ws_size,
                              hipStream_t stream) {
  const float* X    = (const float*)d_in[0];
  const float* W1   = (const float*)d_in[1];
  const float* B1   = (const float*)d_in[2];
  const float* G1   = (const float*)d_in[3];
  const float* BE1  = (const float*)d_in[4];
  const float* W2   = (const float*)d_in[5];
  const float* B2   = (const float*)d_in[6];
  const float* G2   = (const float*)d_in[7];
  const float* BE2  = (const float*)d_in[8];
  const float* WQ   = (const float*)d_in[9];
  const float* WK   = (const float*)d_in[10];
  const float* WV   = (const float*)d_in[11];
  const float* FC1W = (const float*)d_in[12];
  const float* FC1B = (const float*)d_in[13];
  const float* FC2W = (const float*)d_in[14];
  const float* FC2B = (const float*)d_in[15];
  float* OUT = (float*)d_out;

  // ---- workspace carve-out ----
  char* p = (char*)d_ws;
  auto alloc = [&](size_t bytes) -> char* {
    char* r = p;
    p += (bytes + 255) & ~(size_t)255;
    return r;
  };
  float* H1t  = (float*)alloc((size_t)BATCH * NPT * DMID * 4);
  bf16*  H1tb = (bf16*)alloc((size_t)BATCH * NPT * DMID * 2);
  float* Hn   = (float*)alloc((size_t)BATCH * STRD * 4);   // [b*n][256] f32
  bf16*  Htb  = (bf16*)alloc((size_t)BATCH * STRD * 2);    // [b*n][256] bf16
  bf16*  QKt  = (bf16*)alloc((size_t)BATCH * QKS * 2);     // [b][n][512]
  bf16*  Vb   = (bf16*)alloc((size_t)BATCH * STRD * 2);    // [b][e][n]
  bf16*  W2b  = (bf16*)alloc((size_t)DEMB * DMID * 2);
  bf16*  WQKb = (bf16*)alloc((size_t)NSA * 512 * DEMB * 2);
  bf16*  WVb  = (bf16*)alloc((size_t)NSA * DEMB * DEMB * 2);
  float* pS   = (float*)alloc(128 * 64 * 4);
  float* pS2  = (float*)alloc(128 * 64 * 4);
  float* pA2  = (float*)alloc(128 * DEMB * 4);
  float* pB2  = (float*)alloc(128 * DEMB * 4);
  float* sa1  = (float*)alloc(64 * 4);
  float* sb1  = (float*)alloc(64 * 4);
  float* sa2  = (float*)alloc(256 * 4);
  float* sb2  = (float*)alloc(256 * 4);
  float* CM   = (float*)alloc((size_t)BATCH * NPT * 4);
  float* CSi  = (float*)alloc((size_t)BATCH * NPT * 4);
  float* PM   = (float*)alloc((size_t)BATCH * 16 * NPT * 4);
  float* PSm  = (float*)alloc((size_t)BATCH * 16 * NPT * 4);
  float* POOL = (float*)alloc((size_t)BATCH * NPT * 4);
  float* FH   = (float*)alloc((size_t)BATCH * NPT * 4);
  size_t used = (size_t)(p - (char*)d_ws);
  const size_t per_g = (size_t)NN * 2;  // F bf16 (8MB per batch)
  int G = 8;
  while (G > 1 && used + (size_t)G * per_g + 1024 > ws_size) G >>= 1;
  bf16* F = (bf16*)alloc((size_t)G * NN * 2);

  // ---- weight converts ----
  k_cvt<<<(DEMB * DMID + 255) / 256, 256, 0, stream>>>(W2, W2b, DEMB * DMID);
  int nqk = NSA * 512 * DEMB;
  k_cvtqk<<<nqk / 256, 256, 0, stream>>>(WQ, WK, WQKb);
  int nw = NSA * DEMB * DEMB;
  k_cvt<<<(nw + 255) / 256, 256, 0, stream>>>(WV, WVb, nw);

  // ---- conv1 + BN1 + ReLU (-> H1tb bf16 [b*n][64]) ----
  long szh1 = (long)BATCH * NPT * DMID;
  k_conv1t<<<(int)(szh1 / 256), 256, 0, stream>>>(X, W1, B1, H1t);
  k_bn1a<<<128, 256, 0, stream>>>(H1t, pS, pS2);
  k_bn1b<<<1, 64, 0, stream>>>(pS, pS2, G1, BE1, sa1, sb1);
  k_bn1apply<<<(int)(szh1 / 256), 256, 0, stream>>>(H1t, sa1, sb1, H1tb);

  // ---- conv2 (MFMA, [n][e] layout) + BN2 + ReLU -> Hn f32 + Htb bf16 ----
  k_mgemm<2><<<dim3(2, 128, 1), 256, 0, stream>>>(H1tb, 0, DMID, W2b, 0, DMID,
                                                  Hn, 0, DEMB, DMID, B2, nullptr, nullptr, 0);
  k_bn2a<<<128, 256, 0, stream>>>(Hn, pA2, pB2);
  k_bn2b<<<1, 256, 0, stream>>>(pA2, pB2, G2, BE2, sa2, sb2);
  k_bnapply2<<<(int)(BATCH * STRD / 256), 256, 0, stream>>>(Hn, Htb, sa2, sb2);

  // ---- SA layers (no transpose needed; Htb maintained by k_vp epilogue) ----
  for (int l = 0; l < NSA; ++l) {
    // QKt[n][0..511] = Htb . [Wq;Wk]^T  : A=Htb (M=2048/b), B=WQK (N=512)
    k_mgemm<1><<<dim3(4, 16, 8), 256, 0, stream>>>(Htb, STRD, DEMB, WQKb + (long)l * 512 * DEMB, 0, DEMB,
                                                   QKt, QKS, 512, DEMB, nullptr, nullptr, nullptr, 0);
    // V[e][n] : A=Wv (M=256), B=Htb (N=2048)
    k_mgemm<1><<<dim3(16, 2, 8), 256, 0, stream>>>(WVb + (long)l * DEMB * DEMB, 0, DEMB, Htb, STRD, DEMB,
                                                   Vb, STRD, NPT, DEMB, nullptr, nullptr, nullptr, 0);
    for (int b0 = 0; b0 < BATCH; b0 += G) {
      // F[m][n] = sum_a Kt[m][a] Qt[n][a] (= E^T), bf16 + fused exact column stats
      k_mgemm<0><<<dim3(256 * G), 256, 0, stream>>>(QKt + 256 + b0 * QKS, QKS, 512,
                                                    QKt + b0 * QKS, QKS, 512,
                                                    F, NN, NPT, DEMB, nullptr, PM, PSm, G);
      k_cms_fin<<<G * NPT / 256, 256, 0, stream>>>(PM, PSm, CM, CSi);
      // Hn[m][e] += S[m] * sum_n V[e][n] PT[m][n]; Htb = bf16(Hn)
      k_vp<<<dim3(32 * G), 512, 0, stream>>>(F, CM, CSi, Vb + b0 * STRD,
                                             Hn + b0 * STRD, Htb + b0 * STRD, G);
    }
  }

  // ---- head ----
  k_pool<<<(BATCH * NPT) / 4, 256, 0, stream>>>(Hn, POOL);
  k_fc1<<<NPT, 256, 0, stream>>>(POOL, FC1W, FC1B, FH);
  k_fc2<<<BATCH, 256, 0, stream>>>(FH, FC2W, FC2B, OUT);
}